// Round 1
// 360.793 us; speedup vs baseline: 1.0206x; 1.0206x over previous
//
#include <hip/hip_runtime.h>

// Problem dims
#define B_    512
#define S_    50
#define D_    100
#define NS_   12
#define LAST_ 3
#define NADJ_ 12
#define SCALE_ 0.1f

// ---------------------------------------------------------------------------
// Single merged kernel.
//   blocks [0, B_)      : fused local(star) + global(neighbor) branch, 1 per b
//   blocks [B_, 2*B_)   : last-items attention branch, 1 per b
// LDS ~51.8 KB -> 3 blocks/CU (was 61.8 KB -> 2). adj is read directly from
// global (broadcast float2, L2-hot) instead of staging a 10 KB LDS tile.
// All GEMM LDS reads are b128 (4-k steps) instead of scalar b32.
// ---------------------------------------------------------------------------
__global__ __launch_bounds__(256, 3) void fused_all(
    const int* __restrict__ inputs,       // [B,S]
    const float* __restrict__ adj,        // [B,S,S]
    const float* __restrict__ emb,        // [N,D]
    const int* __restrict__ adj_all,      // [N,NS]
    const float* __restrict__ num_w,      // [N,NS]
    const float* __restrict__ sW,         // [2]
    const float* __restrict__ Wa,         // [D,D]
    const float* __restrict__ Wq,         // [D,D]
    const float* __restrict__ Wk,         // [D,D]
    const float* __restrict__ Wg,         // [2D,D]
    const int* __restrict__ last_items,   // [B,LAST]
    const int* __restrict__ adj_items,    // [B,LAST*NADJ]
    const float* __restrict__ Wl,         // [D,D]
    float* __restrict__ out)              // [B,S,D] then [B,D]
{
    __shared__ __align__(16) float hL[S_][D_];    // 20000 B
    __shared__ __align__(16) float hwa[S_][D_];   // 20000 B (h@Wa, later agg)
    __shared__ __align__(16) float ssq[S_][25];   //  5000 B
    __shared__ float star[D_], kb[D_], kq[D_];    //  1200 B
    __shared__ float gate[S_], rinv[S_], rinv2[S_]; // 600 B
    __shared__ int   ids[S_];                     //   200 B
    __shared__ int   nid[S_ * NS_];               //  2400 B
    __shared__ float alf[S_ * NS_];               //  2400 B
    __shared__ float denom;
    // total ~51.8 KB -> 3 blocks/CU

    const int t = threadIdx.x;

    // =====================================================================
    // last-items branch (aliases the shared buffers above)
    // =====================================================================
    if (blockIdx.x >= B_) {
        const int b = blockIdx.x - B_;
        float* ih  = &hL[0][0];            // [3][100]   (300 floats)
        float* ah  = &hL[0][0] + 304;      // [3][12][100] (3600 floats, 16B-aligned)
        float* qL  = &hwa[0][0];           // [3][100]
        float* att = &ssq[0][0];           // [3][12]
        int*   li  = ids;
        int*   ai  = nid;

        if (t < LAST_) li[t] = last_items[b * LAST_ + t];
        if (t < LAST_ * NADJ_) ai[t] = adj_items[b * LAST_ * NADJ_ + t];
        __syncthreads();

        for (int e = t; e < LAST_ * 25; e += 256) {           // 75 quads
            int l = e / 25, dq = e - l * 25;
            ((float4*)ih)[e] = ((const float4*)(emb + li[l] * D_))[dq];
        }
        for (int e = t; e < LAST_ * NADJ_ * 25; e += 256) {   // 900 quads
            int j = e / 25, dq = e - j * 25;
            ((float4*)ah)[e] = ((const float4*)(emb + ai[j] * D_))[dq];
        }
        __syncthreads();

        // q = item_h @ Wl (coalesced column reads over d)
        for (int e = t; e < LAST_ * D_; e += 256) {
            int l = e / D_, d = e - l * D_;
            float a = 0.f;
            for (int k = 0; k < D_; ++k) a = fmaf(ih[l * D_ + k], Wl[k * D_ + d], a);
            qL[e] = a;
        }
        __syncthreads();

        if (t < LAST_ * NADJ_) {
            int l = t / NADJ_;
            const float* ar = ah + t * D_;
            const float* qr = qL + l * D_;
            float a = 0.f;
            for (int d = 0; d < D_; ++d) a = fmaf(qr[d], ar[d], a);
            att[t] = a * SCALE_;
        }
        __syncthreads();

        if (t < LAST_) {
            float mx = -1e30f;
            for (int n = 0; n < NADJ_; ++n) mx = fmaxf(mx, att[t * NADJ_ + n]);
            float ex[NADJ_]; float sm = 0.f;
            for (int n = 0; n < NADJ_; ++n) { ex[n] = expf(att[t * NADJ_ + n] - mx); sm += ex[n]; }
            float inv = 1.f / sm;
            for (int n = 0; n < NADJ_; ++n) att[t * NADJ_ + n] = ex[n] * inv;
        }
        __syncthreads();

        if (t < D_) {
            float acc = 0.f;
            for (int l = 0; l < LAST_; ++l) {
                float a = ih[l * D_ + t];
                for (int n = 0; n < NADJ_; ++n)
                    a = fmaf(att[l * NADJ_ + n], ah[(l * NADJ_ + n) * D_ + t], a);
                acc += a;
            }
            out[B_ * S_ * D_ + b * D_ + t] = acc * (1.f / 3.f);
        }
        return;
    }

    // =====================================================================
    // fused star + neighbor branch
    // =====================================================================
    const int b = blockIdx.x;
    const float s0 = sW[0], s1 = sW[1];

    if (t < S_) ids[t] = inputs[b * S_ + t];
    __syncthreads();

    // denom via ballot (wave 0 only, no serial loop)
    if (t < 64) {
        unsigned long long m = __ballot(t < S_ && ids[t] != 0);
        if (t == 0) denom = fmaxf((float)__popcll(m), 1.f);
    }
    // gather h rows + neighbor ids/weights (all depend only on ids)
    for (int e = t; e < S_ * 25; e += 256) {                  // 1250 quads
        int s = e / 25, dq = e - s * 25;
        ((float4*)&hL[0][0])[e] = ((const float4*)(emb + ids[s] * D_))[dq];
    }
    for (int e = t; e < S_ * NS_; e += 256) {                 // 600
        int r = e / NS_, n = e - r * NS_;
        nid[e] = adj_all[ids[r] * NS_ + n];
        alf[e] = num_w[ids[r] * NS_ + n];
    }
    __syncthreads();

    // star (t<100)  ||  alpha softmax on an otherwise-idle wave (t in [128,178))
    if (t < D_) {
        float a = 0.f;
        for (int s = 0; s < S_; ++s) a += (ids[s] != 0) ? hL[s][t] : 0.f;
        star[t] = a / denom;
    } else if (t >= 128 && t < 128 + S_) {
        int r = t - 128;
        float mx = -1e30f;
#pragma unroll
        for (int n = 0; n < NS_; ++n) mx = fmaxf(mx, alf[r * NS_ + n]);
        float ex[NS_]; float sm = 0.f;
#pragma unroll
        for (int n = 0; n < NS_; ++n) { ex[n] = expf(alf[r * NS_ + n] - mx); sm += ex[n]; }
        float inv = 1.f / sm;
#pragma unroll
        for (int n = 0; n < NS_; ++n) alf[r * NS_ + n] = ex[n] * inv;
    }
    __syncthreads();

    // kb = star @ Wk (coalesced column reads)
    if (t < D_) {
        float a = 0.f;
        for (int k = 0; k < D_; ++k) a = fmaf(star[k], Wk[k * D_ + t], a);
        kb[t] = a;
    }
    __syncthreads();

    // kq[t] = Wq[t,:]·kb
    if (t < D_) {
        float a = 0.f;
        const float4* wr = (const float4*)(Wq + t * D_);
#pragma unroll 5
        for (int j = 0; j < 25; ++j) {
            float4 u = wr[j]; int k = j * 4;
            a = fmaf(u.x, kb[k + 0], a); a = fmaf(u.y, kb[k + 1], a);
            a = fmaf(u.z, kb[k + 2], a); a = fmaf(u.w, kb[k + 3], a);
        }
        kq[t] = a;
    }
    __syncthreads();

    // gate[s] = sigmoid(SCALE * h[s]·kq)  (vectorized row read; readers sync
    // at the barrier after the hwa GEMM)
    if (t < S_) {
        float a = 0.f;
        const float4* hr = (const float4*)&hL[t][0];
#pragma unroll 5
        for (int j = 0; j < 25; ++j) {
            float4 u = hr[j]; int k = j * 4;
            a = fmaf(u.x, kq[k + 0], a); a = fmaf(u.y, kq[k + 1], a);
            a = fmaf(u.z, kq[k + 2], a); a = fmaf(u.w, kq[k + 3], a);
        }
        gate[t] = 1.f / (1.f + expf(-a * SCALE_));
    }

    const bool act = (t < 250);
    int sg = 0, dg = 0, sb = 0, d4 = 0;
    if (act) { sg = t / 25; dg = t - sg * 25; sb = sg * 5; d4 = dg * 4; }

    // ---- hwa = h @ Wa : 4-k steps, b128 LDS reads ----
    if (act) {
        float acc[5][4] = {};
        const float4* WaQ = (const float4*)Wa;
        for (int k = 0; k < D_; k += 4) {
            float4 w0 = WaQ[(k + 0) * 25 + dg];
            float4 w1 = WaQ[(k + 1) * 25 + dg];
            float4 w2 = WaQ[(k + 2) * 25 + dg];
            float4 w3 = WaQ[(k + 3) * 25 + dg];
#pragma unroll
            for (int i = 0; i < 5; ++i) {
                float4 x = *(const float4*)&hL[sb + i][k];
                acc[i][0] = fmaf(x.x,w0.x, fmaf(x.y,w1.x, fmaf(x.z,w2.x, fmaf(x.w,w3.x, acc[i][0]))));
                acc[i][1] = fmaf(x.x,w0.y, fmaf(x.y,w1.y, fmaf(x.z,w2.y, fmaf(x.w,w3.y, acc[i][1]))));
                acc[i][2] = fmaf(x.x,w0.z, fmaf(x.y,w1.z, fmaf(x.z,w2.z, fmaf(x.w,w3.z, acc[i][2]))));
                acc[i][3] = fmaf(x.x,w0.w, fmaf(x.y,w1.w, fmaf(x.z,w2.w, fmaf(x.w,w3.w, acc[i][3]))));
            }
        }
#pragma unroll
        for (int i = 0; i < 5; ++i) {
            float4 v; v.x = acc[i][0]; v.y = acc[i][1]; v.z = acc[i][2]; v.w = acc[i][3];
            *(float4*)&hwa[sb + i][d4] = v;
        }
    }
    __syncthreads();

    // ---- h_n = adj @ hwa; hl = (1-g)*h_n + g*star  (adj from global,
    //      broadcast float2 — rows are 200 B so float4 would be misaligned) ----
    float hl[5][4] = {};
    if (act) {
        const float* adjp = adj + b * S_ * S_;
        for (int k = 0; k < S_; k += 2) {
            float4 w0 = *(const float4*)&hwa[k][d4];
            float4 w1 = *(const float4*)&hwa[k + 1][d4];
#pragma unroll
            for (int i = 0; i < 5; ++i) {
                float2 a2 = *(const float2*)(adjp + (sb + i) * S_ + k);
                hl[i][0] = fmaf(a2.x, w0.x, fmaf(a2.y, w1.x, hl[i][0]));
                hl[i][1] = fmaf(a2.x, w0.y, fmaf(a2.y, w1.y, hl[i][1]));
                hl[i][2] = fmaf(a2.x, w0.z, fmaf(a2.y, w1.z, hl[i][2]));
                hl[i][3] = fmaf(a2.x, w0.w, fmaf(a2.y, w1.w, hl[i][3]));
            }
        }
#pragma unroll
        for (int i = 0; i < 5; ++i) {
            float g = gate[sb + i];
#pragma unroll
            for (int j = 0; j < 4; ++j)
                hl[i][j] = (1.f - g) * hl[i][j] + g * star[d4 + j];
            ssq[sb + i][dg] = hl[i][0]*hl[i][0] + hl[i][1]*hl[i][1]
                            + hl[i][2]*hl[i][2] + hl[i][3]*hl[i][3];
        }
    }
    __syncthreads();

    if (t < S_) {
        float ss = 0.f;
#pragma unroll
        for (int j = 0; j < 25; ++j) ss += ssq[t][j];
        rinv[t] = s0 / fmaxf(sqrtf(ss), 1e-12f);
    }
    __syncthreads();

    // normalize hl in regs; agg = softmax(num_w)·emb[neighbors] -> hwa
    if (act) {
#pragma unroll
        for (int i = 0; i < 5; ++i) {
            float f = rinv[sb + i];
#pragma unroll
            for (int j = 0; j < 4; ++j) hl[i][j] *= f;
        }
#pragma unroll
        for (int i = 0; i < 5; ++i) {
            int row = sb + i;
            float a0 = 0.f, a1 = 0.f, a2 = 0.f, a3 = 0.f;
#pragma unroll
            for (int n = 0; n < NS_; ++n) {
                float4 u = ((const float4*)(emb + nid[row * NS_ + n] * D_))[dg];
                float al = alf[row * NS_ + n];
                a0 = fmaf(al, u.x, a0); a1 = fmaf(al, u.y, a1);
                a2 = fmaf(al, u.z, a2); a3 = fmaf(al, u.w, a3);
            }
            float4 v; v.x = a0; v.y = a1; v.z = a2; v.w = a3;
            *(float4*)&hwa[row][d4] = v;
        }
    }
    __syncthreads();

    // ---- hg = relu([h | agg] @ Wg); 4-k steps, b128 LDS reads ----
    float o[5][4] = {};
    if (act) {
        const float4* WgQ = (const float4*)Wg;
        for (int k = 0; k < D_; k += 4) {
            float4 w0 = WgQ[(k + 0) * 25 + dg];
            float4 w1 = WgQ[(k + 1) * 25 + dg];
            float4 w2 = WgQ[(k + 2) * 25 + dg];
            float4 w3 = WgQ[(k + 3) * 25 + dg];
#pragma unroll
            for (int i = 0; i < 5; ++i) {
                float4 x = *(const float4*)&hL[sb + i][k];
                o[i][0] = fmaf(x.x,w0.x, fmaf(x.y,w1.x, fmaf(x.z,w2.x, fmaf(x.w,w3.x, o[i][0]))));
                o[i][1] = fmaf(x.x,w0.y, fmaf(x.y,w1.y, fmaf(x.z,w2.y, fmaf(x.w,w3.y, o[i][1]))));
                o[i][2] = fmaf(x.x,w0.z, fmaf(x.y,w1.z, fmaf(x.z,w2.z, fmaf(x.w,w3.z, o[i][2]))));
                o[i][3] = fmaf(x.x,w0.w, fmaf(x.y,w1.w, fmaf(x.z,w2.w, fmaf(x.w,w3.w, o[i][3]))));
            }
        }
        for (int k = 0; k < D_; k += 4) {
            float4 w0 = WgQ[(D_ + k + 0) * 25 + dg];
            float4 w1 = WgQ[(D_ + k + 1) * 25 + dg];
            float4 w2 = WgQ[(D_ + k + 2) * 25 + dg];
            float4 w3 = WgQ[(D_ + k + 3) * 25 + dg];
#pragma unroll
            for (int i = 0; i < 5; ++i) {
                float4 x = *(const float4*)&hwa[sb + i][k];   // agg
                o[i][0] = fmaf(x.x,w0.x, fmaf(x.y,w1.x, fmaf(x.z,w2.x, fmaf(x.w,w3.x, o[i][0]))));
                o[i][1] = fmaf(x.x,w0.y, fmaf(x.y,w1.y, fmaf(x.z,w2.y, fmaf(x.w,w3.y, o[i][1]))));
                o[i][2] = fmaf(x.x,w0.z, fmaf(x.y,w1.z, fmaf(x.z,w2.z, fmaf(x.w,w3.z, o[i][2]))));
                o[i][3] = fmaf(x.x,w0.w, fmaf(x.y,w1.w, fmaf(x.z,w2.w, fmaf(x.w,w3.w, o[i][3]))));
            }
        }
#pragma unroll
        for (int i = 0; i < 5; ++i) {
#pragma unroll
            for (int j = 0; j < 4; ++j) o[i][j] = fmaxf(o[i][j], 0.f);
            ssq[sb + i][dg] = o[i][0]*o[i][0] + o[i][1]*o[i][1]
                            + o[i][2]*o[i][2] + o[i][3]*o[i][3];
        }
    }
    __syncthreads();

    if (t < S_) {
        float ss = 0.f;
#pragma unroll
        for (int j = 0; j < 25; ++j) ss += ssq[t][j];
        rinv2[t] = s1 / fmaxf(sqrtf(ss), 1e-12f);
    }
    __syncthreads();

    // ---- combine + store ----
    if (act) {
#pragma unroll
        for (int i = 0; i < 5; ++i) {
            float f = rinv2[sb + i];
            int row = b * S_ + sb + i;
            float4 ov;
            ov.x = hl[i][0] + o[i][0] * f;
            ov.y = hl[i][1] + o[i][1] * f;
            ov.z = hl[i][2] + o[i][2] * f;
            ov.w = hl[i][3] + o[i][3] * f;
            ((float4*)(out + row * D_))[dg] = ov;
        }
    }
}

// ---------------------------------------------------------------------------
extern "C" void kernel_launch(void* const* d_in, const int* in_sizes, int n_in,
                              void* d_out, int out_size, void* d_ws, size_t ws_size,
                              hipStream_t stream) {
    (void)in_sizes; (void)n_in; (void)out_size; (void)d_ws; (void)ws_size;
    const int* inputs     = (const int*)d_in[0];
    const float* adj      = (const float*)d_in[1];
    // d_in[2] = item (unused by reference)
    const int* last_items = (const int*)d_in[3];
    const int* adj_items  = (const int*)d_in[4];
    const float* emb      = (const float*)d_in[5];
    const float* sW       = (const float*)d_in[6];
    const float* Wa       = (const float*)d_in[7];
    const float* Wq       = (const float*)d_in[8];
    const float* Wk       = (const float*)d_in[9];
    const float* Wg       = (const float*)d_in[10];
    const float* Wl       = (const float*)d_in[11];
    const int* adj_all    = (const int*)d_in[12];
    const float* num_w    = (const float*)d_in[13];

    float* out = (float*)d_out;

    fused_all<<<2 * B_, 256, 0, stream>>>(inputs, adj, emb, adj_all, num_w,
                                          sW, Wa, Wq, Wk, Wg,
                                          last_items, adj_items, Wl, out);
}

// Round 2
// 353.365 us; speedup vs baseline: 1.0420x; 1.0210x over previous
//
#include <hip/hip_runtime.h>
#include <hip/hip_fp16.h>

// Problem dims
#define B_    512
#define S_    50
#define D_    100
#define NS_   12
#define LAST_ 3
#define NADJ_ 12
#define SCALE_ 0.1f

// 5-row x 4-col FMA group for one 4-k slab
#define GEMM_STEP(ACC, BUF, K, W0, W1, W2, W3)                                      \
    _Pragma("unroll")                                                                \
    for (int i = 0; i < 5; ++i) {                                                    \
        float4 x = *(const float4*)&BUF[sb + i][K];                                  \
        ACC[i][0] = fmaf(x.x,W0.x, fmaf(x.y,W1.x, fmaf(x.z,W2.x, fmaf(x.w,W3.x, ACC[i][0])))); \
        ACC[i][1] = fmaf(x.x,W0.y, fmaf(x.y,W1.y, fmaf(x.z,W2.y, fmaf(x.w,W3.y, ACC[i][1])))); \
        ACC[i][2] = fmaf(x.x,W0.z, fmaf(x.y,W1.z, fmaf(x.z,W2.z, fmaf(x.w,W3.z, ACC[i][2])))); \
        ACC[i][3] = fmaf(x.x,W0.w, fmaf(x.y,W1.w, fmaf(x.z,W2.w, fmaf(x.w,W3.w, ACC[i][3])))); \
    }

// ---------------------------------------------------------------------------
// Single merged kernel.
//   blocks [0, B_)      : fused local(star) + global(neighbor) branch, 1 per b
//   blocks [B_, 2*B_)   : last-items attention branch, 1 per b
// LDS ~51.8 KB -> 3 blocks/CU. adj staged in LDS as fp16, union'd with ssq
// (disjoint lifetimes, barrier-separated). Weight loads software-pipelined.
// ---------------------------------------------------------------------------
__global__ __launch_bounds__(256, 3) void fused_all(
    const int* __restrict__ inputs,       // [B,S]
    const float* __restrict__ adj,        // [B,S,S]
    const float* __restrict__ emb,        // [N,D]
    const int* __restrict__ adj_all,      // [N,NS]
    const float* __restrict__ num_w,      // [N,NS]
    const float* __restrict__ sW,         // [2]
    const float* __restrict__ Wa,         // [D,D]
    const float* __restrict__ Wq,         // [D,D]
    const float* __restrict__ Wk,         // [D,D]
    const float* __restrict__ Wg,         // [2D,D]
    const int* __restrict__ last_items,   // [B,LAST]
    const int* __restrict__ adj_items,    // [B,LAST*NADJ]
    const float* __restrict__ Wl,         // [D,D]
    float* __restrict__ out)              // [B,S,D] then [B,D]
{
    __shared__ __align__(16) float hL[S_][D_];    // 20000 B
    __shared__ __align__(16) float hwa[S_][D_];   // 20000 B (h@Wa, later agg)
    __shared__ __align__(16) union UAS {          //  5000 B
        __half adjH[S_][S_];                      //  adj tile (fp16), dead after adj-GEMM
        float  ssq[S_][25];                       //  row-sumsq partials, live after
    } u;
    __shared__ float star[D_], kb[D_], kq[D_];    //  1200 B
    __shared__ float gate[S_], rinv[S_], rinv2[S_]; // 600 B
    __shared__ int   ids[S_];                     //   200 B
    __shared__ int   nid[S_ * NS_];               //  2400 B
    __shared__ float alf[S_ * NS_];               //  2400 B
    __shared__ float denom;
    // total ~51.8 KB -> 3 blocks/CU

    const int t = threadIdx.x;

    // =====================================================================
    // last-items branch (aliases the shared buffers above)
    // =====================================================================
    if (blockIdx.x >= B_) {
        const int b = blockIdx.x - B_;
        float* ih  = &hL[0][0];            // [3][100]
        float* ah  = &hL[0][0] + 304;      // [3][12][100] (16B-aligned)
        float* qL  = &hwa[0][0];           // [3][100]
        float* att = &u.ssq[0][0];         // [3][12]
        int*   li  = ids;
        int*   ai  = nid;

        if (t < LAST_) li[t] = last_items[b * LAST_ + t];
        if (t < LAST_ * NADJ_) ai[t] = adj_items[b * LAST_ * NADJ_ + t];
        __syncthreads();

        for (int e = t; e < LAST_ * 25; e += 256) {           // 75 quads
            int l = e / 25, dq = e - l * 25;
            ((float4*)ih)[e] = ((const float4*)(emb + li[l] * D_))[dq];
        }
        for (int e = t; e < LAST_ * NADJ_ * 25; e += 256) {   // 900 quads
            int j = e / 25, dq = e - j * 25;
            ((float4*)ah)[e] = ((const float4*)(emb + ai[j] * D_))[dq];
        }
        __syncthreads();

        // q = item_h @ Wl (coalesced column reads over d)
        for (int e = t; e < LAST_ * D_; e += 256) {
            int l = e / D_, d = e - l * D_;
            float a = 0.f;
            for (int k = 0; k < D_; ++k) a = fmaf(ih[l * D_ + k], Wl[k * D_ + d], a);
            qL[e] = a;
        }
        __syncthreads();

        if (t < LAST_ * NADJ_) {
            int l = t / NADJ_;
            const float* ar = ah + t * D_;
            const float* qr = qL + l * D_;
            float a = 0.f;
            for (int d = 0; d < D_; ++d) a = fmaf(qr[d], ar[d], a);
            att[t] = a * SCALE_;
        }
        __syncthreads();

        if (t < LAST_) {
            float mx = -1e30f;
            for (int n = 0; n < NADJ_; ++n) mx = fmaxf(mx, att[t * NADJ_ + n]);
            float ex[NADJ_]; float sm = 0.f;
            for (int n = 0; n < NADJ_; ++n) { ex[n] = __expf(att[t * NADJ_ + n] - mx); sm += ex[n]; }
            float inv = 1.f / sm;
            for (int n = 0; n < NADJ_; ++n) att[t * NADJ_ + n] = ex[n] * inv;
        }
        __syncthreads();

        if (t < D_) {
            float acc = 0.f;
            for (int l = 0; l < LAST_; ++l) {
                float a = ih[l * D_ + t];
                for (int n = 0; n < NADJ_; ++n)
                    a = fmaf(att[l * NADJ_ + n], ah[(l * NADJ_ + n) * D_ + t], a);
                acc += a;
            }
            out[B_ * S_ * D_ + b * D_ + t] = acc * (1.f / 3.f);
        }
        return;
    }

    // =====================================================================
    // fused star + neighbor branch
    // =====================================================================
    const int b = blockIdx.x;
    const float s0 = sW[0], s1 = sW[1];

    const bool act = (t < 250);
    int sg = 0, dg = 0, sb = 0, d4 = 0;
    if (act) { sg = t / 25; dg = t - sg * 25; sb = sg * 5; d4 = dg * 4; }

    // Early prefetch of Wa k-group 0 (L2-latency hides under gather/star/gate)
    const float4* WaQ = (const float4*)Wa;
    float4 wa0, wa1, wa2, wa3;
    if (act) {
        wa0 = WaQ[0 * 25 + dg]; wa1 = WaQ[1 * 25 + dg];
        wa2 = WaQ[2 * 25 + dg]; wa3 = WaQ[3 * 25 + dg];
    }

    if (t < S_) ids[t] = inputs[b * S_ + t];
    __syncthreads();

    // denom via ballot (wave 0)
    if (t < 64) {
        unsigned long long m = __ballot(t < S_ && ids[t] != 0);
        if (t == 0) denom = fmaxf((float)__popcll(m), 1.f);
    }
    // gather h rows + adj tile (->fp16) + neighbor ids/weights
    for (int e = t; e < S_ * 25; e += 256) {                  // 1250 quads
        int s = e / 25, dq = e - s * 25;
        ((float4*)&hL[0][0])[e] = ((const float4*)(emb + ids[s] * D_))[dq];
    }
    {
        __half2* dst = (__half2*)&u.adjH[0][0];
        const float4* src = (const float4*)(adj + b * S_ * S_);
        for (int e = t; e < S_ * S_ / 4; e += 256) {          // 625 quads
            float4 v = src[e];
            dst[2 * e]     = __floats2half2_rn(v.x, v.y);
            dst[2 * e + 1] = __floats2half2_rn(v.z, v.w);
        }
    }
    for (int e = t; e < S_ * NS_; e += 256) {                 // 600
        int r = e / NS_, n = e - r * NS_;
        nid[e] = adj_all[ids[r] * NS_ + n];
        alf[e] = num_w[ids[r] * NS_ + n];
    }
    __syncthreads();

    // star (t<100)  ||  alpha softmax on an otherwise-idle wave (t in [128,178))
    if (t < D_) {
        float a = 0.f;
        for (int s = 0; s < S_; ++s) a += (ids[s] != 0) ? hL[s][t] : 0.f;
        star[t] = a / denom;
    } else if (t >= 128 && t < 128 + S_) {
        int r = t - 128;
        float mx = -1e30f;
#pragma unroll
        for (int n = 0; n < NS_; ++n) mx = fmaxf(mx, alf[r * NS_ + n]);
        float ex[NS_]; float sm = 0.f;
#pragma unroll
        for (int n = 0; n < NS_; ++n) { ex[n] = __expf(alf[r * NS_ + n] - mx); sm += ex[n]; }
        float inv = 1.f / sm;
#pragma unroll
        for (int n = 0; n < NS_; ++n) alf[r * NS_ + n] = ex[n] * inv;
    }
    __syncthreads();

    // kb = star @ Wk (coalesced column reads)
    if (t < D_) {
        float a = 0.f;
        for (int k = 0; k < D_; ++k) a = fmaf(star[k], Wk[k * D_ + t], a);
        kb[t] = a;
    }
    __syncthreads();

    // kq[t] = Wq[t,:]·kb
    if (t < D_) {
        float a = 0.f;
        const float4* wr = (const float4*)(Wq + t * D_);
#pragma unroll 5
        for (int j = 0; j < 25; ++j) {
            float4 uq = wr[j]; int k = j * 4;
            a = fmaf(uq.x, kb[k + 0], a); a = fmaf(uq.y, kb[k + 1], a);
            a = fmaf(uq.z, kb[k + 2], a); a = fmaf(uq.w, kb[k + 3], a);
        }
        kq[t] = a;
    }
    __syncthreads();

    // gate[s] = sigmoid(SCALE * h[s]·kq)  (readers sync at post-hwa barrier)
    if (t < S_) {
        float a = 0.f;
        const float4* hr = (const float4*)&hL[t][0];
#pragma unroll 5
        for (int j = 0; j < 25; ++j) {
            float4 uq = hr[j]; int k = j * 4;
            a = fmaf(uq.x, kq[k + 0], a); a = fmaf(uq.y, kq[k + 1], a);
            a = fmaf(uq.z, kq[k + 2], a); a = fmaf(uq.w, kq[k + 3], a);
        }
        gate[t] = 1.f / (1.f + __expf(-a * SCALE_));
    }

    // ---- hwa = h @ Wa : depth-1 weight prefetch, b128 LDS reads ----
    if (act) {
        float acc[5][4] = {};
        for (int k = 0; k < 96; k += 4) {
            float4 n0 = WaQ[(k + 4) * 25 + dg], n1 = WaQ[(k + 5) * 25 + dg],
                   n2 = WaQ[(k + 6) * 25 + dg], n3 = WaQ[(k + 7) * 25 + dg];
            GEMM_STEP(acc, hL, k, wa0, wa1, wa2, wa3)
            wa0 = n0; wa1 = n1; wa2 = n2; wa3 = n3;
        }
        GEMM_STEP(acc, hL, 96, wa0, wa1, wa2, wa3)
#pragma unroll
        for (int i = 0; i < 5; ++i) {
            float4 v; v.x = acc[i][0]; v.y = acc[i][1]; v.z = acc[i][2]; v.w = acc[i][3];
            *(float4*)&hwa[sb + i][d4] = v;
        }
    }
    __syncthreads();

    // ---- h_n = adj @ hwa (adjH fp16 broadcast reads); hl = (1-g)*h_n + g*star ----
    float hl[5][4] = {};
    if (act) {
        for (int k = 0; k < S_; k += 2) {
            float4 w0 = *(const float4*)&hwa[k][d4];
            float4 w1 = *(const float4*)&hwa[k + 1][d4];
#pragma unroll
            for (int i = 0; i < 5; ++i) {
                float2 a2 = __half22float2(*(const __half2*)&u.adjH[sb + i][k]);
                hl[i][0] = fmaf(a2.x, w0.x, fmaf(a2.y, w1.x, hl[i][0]));
                hl[i][1] = fmaf(a2.x, w0.y, fmaf(a2.y, w1.y, hl[i][1]));
                hl[i][2] = fmaf(a2.x, w0.z, fmaf(a2.y, w1.z, hl[i][2]));
                hl[i][3] = fmaf(a2.x, w0.w, fmaf(a2.y, w1.w, hl[i][3]));
            }
        }
#pragma unroll
        for (int i = 0; i < 5; ++i) {
            float g = gate[sb + i];
#pragma unroll
            for (int j = 0; j < 4; ++j)
                hl[i][j] = (1.f - g) * hl[i][j] + g * star[d4 + j];
        }
    }
    __syncthreads();   // all adjH reads complete before ssq overwrite (union)

    // ---- ssq write + agg gather + Wg group-0 prefetch (one phase) ----
    const float4* WgQ = (const float4*)Wg;
    float4 wg0, wg1, wg2, wg3;
    if (act) {
        wg0 = WgQ[0 * 25 + dg]; wg1 = WgQ[1 * 25 + dg];
        wg2 = WgQ[2 * 25 + dg]; wg3 = WgQ[3 * 25 + dg];
#pragma unroll
        for (int i = 0; i < 5; ++i)
            u.ssq[sb + i][dg] = hl[i][0]*hl[i][0] + hl[i][1]*hl[i][1]
                              + hl[i][2]*hl[i][2] + hl[i][3]*hl[i][3];
#pragma unroll
        for (int i = 0; i < 5; ++i) {
            int row = sb + i;
            float a0 = 0.f, a1 = 0.f, a2 = 0.f, a3 = 0.f;
#pragma unroll
            for (int n = 0; n < NS_; ++n) {
                float4 uq = ((const float4*)(emb + nid[row * NS_ + n] * D_))[dg];
                float al = alf[row * NS_ + n];
                a0 = fmaf(al, uq.x, a0); a1 = fmaf(al, uq.y, a1);
                a2 = fmaf(al, uq.z, a2); a3 = fmaf(al, uq.w, a3);
            }
            float4 v; v.x = a0; v.y = a1; v.z = a2; v.w = a3;
            *(float4*)&hwa[row][d4] = v;   // hwa reads finished in adj-GEMM
        }
    }
    __syncthreads();

    if (t < S_) {
        float ss = 0.f;
#pragma unroll
        for (int j = 0; j < 25; ++j) ss += u.ssq[t][j];
        rinv[t] = s0 / fmaxf(sqrtf(ss), 1e-12f);
    }
    __syncthreads();

    // ---- normalize hl; hg = relu([h | agg] @ Wg) with weight prefetch ----
    float o[5][4] = {};
    if (act) {
#pragma unroll
        for (int i = 0; i < 5; ++i) {
            float f = rinv[sb + i];
#pragma unroll
            for (int j = 0; j < 4; ++j) hl[i][j] *= f;
        }
        for (int k = 0; k < 96; k += 4) {
            float4 n0 = WgQ[(k + 4) * 25 + dg], n1 = WgQ[(k + 5) * 25 + dg],
                   n2 = WgQ[(k + 6) * 25 + dg], n3 = WgQ[(k + 7) * 25 + dg];
            GEMM_STEP(o, hL, k, wg0, wg1, wg2, wg3)
            wg0 = n0; wg1 = n1; wg2 = n2; wg3 = n3;
        }
        {   // seam: finish h-half k=96, prefetch agg-half group 0
            float4 n0 = WgQ[100 * 25 + dg], n1 = WgQ[101 * 25 + dg],
                   n2 = WgQ[102 * 25 + dg], n3 = WgQ[103 * 25 + dg];
            GEMM_STEP(o, hL, 96, wg0, wg1, wg2, wg3)
            wg0 = n0; wg1 = n1; wg2 = n2; wg3 = n3;
        }
        for (int k = 0; k < 96; k += 4) {
            float4 n0 = WgQ[(100 + k + 4) * 25 + dg], n1 = WgQ[(100 + k + 5) * 25 + dg],
                   n2 = WgQ[(100 + k + 6) * 25 + dg], n3 = WgQ[(100 + k + 7) * 25 + dg];
            GEMM_STEP(o, hwa, k, wg0, wg1, wg2, wg3)
            wg0 = n0; wg1 = n1; wg2 = n2; wg3 = n3;
        }
        GEMM_STEP(o, hwa, 96, wg0, wg1, wg2, wg3)
#pragma unroll
        for (int i = 0; i < 5; ++i) {
#pragma unroll
            for (int j = 0; j < 4; ++j) o[i][j] = fmaxf(o[i][j], 0.f);
            u.ssq[sb + i][dg] = o[i][0]*o[i][0] + o[i][1]*o[i][1]
                              + o[i][2]*o[i][2] + o[i][3]*o[i][3];
        }
    }
    __syncthreads();

    if (t < S_) {
        float ss = 0.f;
#pragma unroll
        for (int j = 0; j < 25; ++j) ss += u.ssq[t][j];
        rinv2[t] = s1 / fmaxf(sqrtf(ss), 1e-12f);
    }
    __syncthreads();

    // ---- combine + store ----
    if (act) {
#pragma unroll
        for (int i = 0; i < 5; ++i) {
            float f = rinv2[sb + i];
            int row = b * S_ + sb + i;
            float4 ov;
            ov.x = hl[i][0] + o[i][0] * f;
            ov.y = hl[i][1] + o[i][1] * f;
            ov.z = hl[i][2] + o[i][2] * f;
            ov.w = hl[i][3] + o[i][3] * f;
            ((float4*)(out + row * D_))[dg] = ov;
        }
    }
}

// ---------------------------------------------------------------------------
extern "C" void kernel_launch(void* const* d_in, const int* in_sizes, int n_in,
                              void* d_out, int out_size, void* d_ws, size_t ws_size,
                              hipStream_t stream) {
    (void)in_sizes; (void)n_in; (void)out_size; (void)d_ws; (void)ws_size;
    const int* inputs     = (const int*)d_in[0];
    const float* adj      = (const float*)d_in[1];
    // d_in[2] = item (unused by reference)
    const int* last_items = (const int*)d_in[3];
    const int* adj_items  = (const int*)d_in[4];
    const float* emb      = (const float*)d_in[5];
    const float* sW       = (const float*)d_in[6];
    const float* Wa       = (const float*)d_in[7];
    const float* Wq       = (const float*)d_in[8];
    const float* Wk       = (const float*)d_in[9];
    const float* Wg       = (const float*)d_in[10];
    const float* Wl       = (const float*)d_in[11];
    const int* adj_all    = (const int*)d_in[12];
    const float* num_w    = (const float*)d_in[13];

    float* out = (float*)d_out;

    fused_all<<<2 * B_, 256, 0, stream>>>(inputs, adj, emb, adj_all, num_w,
                                          sW, Wa, Wq, Wk, Wg,
                                          last_items, adj_items, Wl, out);
}

// Round 3
// 343.699 us; speedup vs baseline: 1.0713x; 1.0281x over previous
//
#include <hip/hip_runtime.h>
#include <hip/hip_fp16.h>

// Problem dims
#define B_    512
#define S_    50
#define D_    100
#define NS_   12
#define LAST_ 3
#define NADJ_ 12
#define SCALE_ 0.1f

typedef __attribute__((ext_vector_type(4))) float f4;

__device__ __forceinline__ f4 ntload4(const float* p) {
    return __builtin_nontemporal_load((const f4*)p);
}

// 5-row x 4-col FMA group for one 4-k slab
#define GEMM_STEP(ACC, BUF, K, W0, W1, W2, W3)                                      \
    _Pragma("unroll")                                                                \
    for (int i = 0; i < 5; ++i) {                                                    \
        float4 x = *(const float4*)&BUF[sb + i][K];                                  \
        ACC[i][0] = fmaf(x.x,W0.x, fmaf(x.y,W1.x, fmaf(x.z,W2.x, fmaf(x.w,W3.x, ACC[i][0])))); \
        ACC[i][1] = fmaf(x.x,W0.y, fmaf(x.y,W1.y, fmaf(x.z,W2.y, fmaf(x.w,W3.y, ACC[i][1])))); \
        ACC[i][2] = fmaf(x.x,W0.z, fmaf(x.y,W1.z, fmaf(x.z,W2.z, fmaf(x.w,W3.z, ACC[i][2])))); \
        ACC[i][3] = fmaf(x.x,W0.w, fmaf(x.y,W1.w, fmaf(x.z,W2.w, fmaf(x.w,W3.w, ACC[i][3])))); \
    }

// agg-gather pipeline pieces (I must be a literal 0..4; q/agg in registers)
#define AGG_ISSUE(I)                                                                 \
    {   int base = (sb + (I)) * NS_;                                                 \
        _Pragma("unroll")                                                            \
        for (int n = 0; n < NS_; ++n)                                                \
            q[n] = ntload4(emb + nid[base + n] * D_ + d4);                           \
    }
#define AGG_CONSUME(I)                                                               \
    {   int base = (sb + (I)) * NS_;                                                 \
        float mx = -1e30f;                                                           \
        _Pragma("unroll")                                                            \
        for (int n = 0; n < NS_; ++n) mx = fmaxf(mx, alf[base + n]);                 \
        float agw[NS_]; float sm = 0.f;                                              \
        _Pragma("unroll")                                                            \
        for (int n = 0; n < NS_; ++n) { agw[n] = __expf(alf[base + n] - mx); sm += agw[n]; } \
        float inv = 1.f / sm;                                                        \
        _Pragma("unroll")                                                            \
        for (int n = 0; n < NS_; ++n) {                                              \
            float w = agw[n] * inv;                                                  \
            agg[I][0] = fmaf(w, q[n].x, agg[I][0]);                                  \
            agg[I][1] = fmaf(w, q[n].y, agg[I][1]);                                  \
            agg[I][2] = fmaf(w, q[n].z, agg[I][2]);                                  \
            agg[I][3] = fmaf(w, q[n].w, agg[I][3]);                                  \
        }                                                                            \
    }

// ---------------------------------------------------------------------------
// Single merged kernel.
//   blocks [0, B_)      : fused local(star) + global(neighbor) branch, 1 per b
//   blocks [B_, 2*B_)   : last-items attention branch, 1 per b
// LDS ~51.8 KB -> 3 blocks/CU. adj staged fp16 union'd with ssq. Neighbor
// gather software-pipelined across the star-chain phases (regs), NT loads
// for all single-use streams so weights stay L2-resident.
// ---------------------------------------------------------------------------
__global__ __launch_bounds__(256, 3) void fused_all(
    const int* __restrict__ inputs,       // [B,S]
    const float* __restrict__ adj,        // [B,S,S]
    const float* __restrict__ emb,        // [N,D]
    const int* __restrict__ adj_all,      // [N,NS]
    const float* __restrict__ num_w,      // [N,NS]
    const float* __restrict__ sW,         // [2]
    const float* __restrict__ Wa,         // [D,D]
    const float* __restrict__ Wq,         // [D,D]
    const float* __restrict__ Wk,         // [D,D]
    const float* __restrict__ Wg,         // [2D,D]
    const int* __restrict__ last_items,   // [B,LAST]
    const int* __restrict__ adj_items,    // [B,LAST*NADJ]
    const float* __restrict__ Wl,         // [D,D]
    float* __restrict__ out)              // [B,S,D] then [B,D]
{
    __shared__ __align__(16) float hL[S_][D_];    // 20000 B
    __shared__ __align__(16) float hwa[S_][D_];   // 20000 B (h@Wa, later agg)
    __shared__ __align__(16) union UAS {          //  5000 B
        __half adjH[S_][S_];                      //  adj tile (fp16), dead after adj-GEMM
        float  ssq[S_][25];                       //  row-sumsq partials, live after
    } u;
    __shared__ float star[D_], kb[D_], kq[D_];    //  1200 B
    __shared__ float gate[S_], rinv[S_], rinv2[S_]; // 600 B
    __shared__ int   ids[S_];                     //   200 B
    __shared__ int   nid[S_ * NS_];               //  2400 B
    __shared__ float alf[S_ * NS_];               //  2400 B (RAW num_w)
    __shared__ float denom;
    // total ~51.8 KB -> 3 blocks/CU

    const int t = threadIdx.x;

    // =====================================================================
    // last-items branch (aliases the shared buffers above)
    // =====================================================================
    if (blockIdx.x >= B_) {
        const int b = blockIdx.x - B_;
        float* ih  = &hL[0][0];            // [3][100]
        float* ah  = &hL[0][0] + 304;      // [3][12][100] (16B-aligned)
        float* qL  = &hwa[0][0];           // [3][100]
        float* att = &u.ssq[0][0];         // [3][12]
        int*   li  = ids;
        int*   ai  = nid;

        if (t < LAST_) li[t] = last_items[b * LAST_ + t];
        if (t < LAST_ * NADJ_) ai[t] = adj_items[b * LAST_ * NADJ_ + t];
        __syncthreads();

        for (int e = t; e < LAST_ * 25; e += 256) {           // 75 quads
            int l = e / 25, dq = e - l * 25;
            ((f4*)ih)[e] = ntload4(emb + li[l] * D_ + dq * 4);
        }
        for (int e = t; e < LAST_ * NADJ_ * 25; e += 256) {   // 900 quads
            int j = e / 25, dq = e - j * 25;
            ((f4*)ah)[e] = ntload4(emb + ai[j] * D_ + dq * 4);
        }
        __syncthreads();

        // q = item_h @ Wl (coalesced column reads over d)
        for (int e = t; e < LAST_ * D_; e += 256) {
            int l = e / D_, d = e - l * D_;
            float a = 0.f;
            for (int k = 0; k < D_; ++k) a = fmaf(ih[l * D_ + k], Wl[k * D_ + d], a);
            qL[e] = a;
        }
        __syncthreads();

        if (t < LAST_ * NADJ_) {
            int l = t / NADJ_;
            const float* ar = ah + t * D_;
            const float* qr = qL + l * D_;
            float a = 0.f;
            for (int d = 0; d < D_; ++d) a = fmaf(qr[d], ar[d], a);
            att[t] = a * SCALE_;
        }
        __syncthreads();

        if (t < LAST_) {
            float mx = -1e30f;
            for (int n = 0; n < NADJ_; ++n) mx = fmaxf(mx, att[t * NADJ_ + n]);
            float ex[NADJ_]; float sm = 0.f;
            for (int n = 0; n < NADJ_; ++n) { ex[n] = __expf(att[t * NADJ_ + n] - mx); sm += ex[n]; }
            float inv = 1.f / sm;
            for (int n = 0; n < NADJ_; ++n) att[t * NADJ_ + n] = ex[n] * inv;
        }
        __syncthreads();

        if (t < D_) {
            float acc = 0.f;
            for (int l = 0; l < LAST_; ++l) {
                float a = ih[l * D_ + t];
                for (int n = 0; n < NADJ_; ++n)
                    a = fmaf(att[l * NADJ_ + n], ah[(l * NADJ_ + n) * D_ + t], a);
                acc += a;
            }
            __builtin_nontemporal_store(acc * (1.f / 3.f),
                                        out + B_ * S_ * D_ + b * D_ + t);
        }
        return;
    }

    // =====================================================================
    // fused star + neighbor branch
    // =====================================================================
    const int b = blockIdx.x;
    const float s0 = sW[0], s1 = sW[1];

    const bool act = (t < 250);
    int sg = 0, dg = 0, sb = 0, d4 = 0;
    if (act) { sg = t / 25; dg = t - sg * 25; sb = sg * 5; d4 = dg * 4; }

    // Early prefetch of Wa k-group 0 (L2-latency hides under gather/star/gate)
    const float4* WaQ = (const float4*)Wa;
    float4 wa0, wa1, wa2, wa3;
    if (act) {
        wa0 = WaQ[0 * 25 + dg]; wa1 = WaQ[1 * 25 + dg];
        wa2 = WaQ[2 * 25 + dg]; wa3 = WaQ[3 * 25 + dg];
    }

    if (t < S_) ids[t] = inputs[b * S_ + t];
    __syncthreads();

    // denom via ballot (wave 0)
    if (t < 64) {
        unsigned long long m = __ballot(t < S_ && ids[t] != 0);
        if (t == 0) denom = fmaxf((float)__popcll(m), 1.f);
    }
    // gather h rows (NT) + adj tile (->fp16, NT) + neighbor ids/raw weights
    for (int e = t; e < S_ * 25; e += 256) {                  // 1250 quads
        int s = e / 25, dq = e - s * 25;
        ((f4*)&hL[0][0])[e] = ntload4(emb + ids[s] * D_ + dq * 4);
    }
    {
        __half2* dst = (__half2*)&u.adjH[0][0];
        const float* src = adj + b * S_ * S_;
        for (int e = t; e < S_ * S_ / 4; e += 256) {          // 625 quads
            f4 v = ntload4(src + e * 4);
            dst[2 * e]     = __floats2half2_rn(v.x, v.y);
            dst[2 * e + 1] = __floats2half2_rn(v.z, v.w);
        }
    }
    for (int e = t; e < S_ * NS_; e += 256) {                 // 600
        int r = e / NS_, n = e - r * NS_;
        nid[e] = adj_all[ids[r] * NS_ + n];
        alf[e] = num_w[ids[r] * NS_ + n];
    }
    __syncthreads();

    // pipelined neighbor gather state (registers)
    f4 q[NS_];
    float agg[5][4] = {};

    // ---- phase 3: star (t<100)  ||  issue gather row 0 ----
    if (act) AGG_ISSUE(0)
    if (t < D_) {
        float a = 0.f;
        for (int s = 0; s < S_; ++s) a += (ids[s] != 0) ? hL[s][t] : 0.f;
        star[t] = a / denom;
    }
    __syncthreads();

    // ---- phase 4: kb = star @ Wk  ||  consume 0, issue 1 ----
    if (t < D_) {
        float a = 0.f;
        for (int k = 0; k < D_; ++k) a = fmaf(star[k], Wk[k * D_ + t], a);
        kb[t] = a;
    }
    if (act) { AGG_CONSUME(0) AGG_ISSUE(1) }
    __syncthreads();

    // ---- phase 5: kq[t] = Wq[t,:]·kb  ||  consume 1, issue 2 ----
    if (t < D_) {
        float a = 0.f;
        const float4* wr = (const float4*)(Wq + t * D_);
#pragma unroll 5
        for (int j = 0; j < 25; ++j) {
            float4 uq = wr[j]; int k = j * 4;
            a = fmaf(uq.x, kb[k + 0], a); a = fmaf(uq.y, kb[k + 1], a);
            a = fmaf(uq.z, kb[k + 2], a); a = fmaf(uq.w, kb[k + 3], a);
        }
        kq[t] = a;
    }
    if (act) { AGG_CONSUME(1) AGG_ISSUE(2) }
    __syncthreads();

    // ---- phase 6: gate; consume 2; hwa = h@Wa; issue 3 ----
    if (t < S_) {
        float a = 0.f;
        const float4* hr = (const float4*)&hL[t][0];
#pragma unroll 5
        for (int j = 0; j < 25; ++j) {
            float4 uq = hr[j]; int k = j * 4;
            a = fmaf(uq.x, kq[k + 0], a); a = fmaf(uq.y, kq[k + 1], a);
            a = fmaf(uq.z, kq[k + 2], a); a = fmaf(uq.w, kq[k + 3], a);
        }
        gate[t] = 1.f / (1.f + __expf(-a * SCALE_));
    }
    if (act) {
        AGG_CONSUME(2)
        float acc[5][4] = {};
        for (int k = 0; k < 96; k += 4) {
            float4 n0 = WaQ[(k + 4) * 25 + dg], n1 = WaQ[(k + 5) * 25 + dg],
                   n2 = WaQ[(k + 6) * 25 + dg], n3 = WaQ[(k + 7) * 25 + dg];
            GEMM_STEP(acc, hL, k, wa0, wa1, wa2, wa3)
            wa0 = n0; wa1 = n1; wa2 = n2; wa3 = n3;
        }
        GEMM_STEP(acc, hL, 96, wa0, wa1, wa2, wa3)
#pragma unroll
        for (int i = 0; i < 5; ++i) {
            float4 v; v.x = acc[i][0]; v.y = acc[i][1]; v.z = acc[i][2]; v.w = acc[i][3];
            *(float4*)&hwa[sb + i][d4] = v;
        }
        AGG_ISSUE(3)
    }
    __syncthreads();

    // ---- phase 7: h_n = adj @ hwa; hl combine; consume 3, issue 4 ----
    float hl[5][4] = {};
    if (act) {
        for (int k = 0; k < S_; k += 2) {
            float4 w0 = *(const float4*)&hwa[k][d4];
            float4 w1 = *(const float4*)&hwa[k + 1][d4];
#pragma unroll
            for (int i = 0; i < 5; ++i) {
                float2 a2 = __half22float2(*(const __half2*)&u.adjH[sb + i][k]);
                hl[i][0] = fmaf(a2.x, w0.x, fmaf(a2.y, w1.x, hl[i][0]));
                hl[i][1] = fmaf(a2.x, w0.y, fmaf(a2.y, w1.y, hl[i][1]));
                hl[i][2] = fmaf(a2.x, w0.z, fmaf(a2.y, w1.z, hl[i][2]));
                hl[i][3] = fmaf(a2.x, w0.w, fmaf(a2.y, w1.w, hl[i][3]));
            }
        }
#pragma unroll
        for (int i = 0; i < 5; ++i) {
            float g = gate[sb + i];
#pragma unroll
            for (int j = 0; j < 4; ++j)
                hl[i][j] = (1.f - g) * hl[i][j] + g * star[d4 + j];
        }
        AGG_CONSUME(3) AGG_ISSUE(4)
    }
    __syncthreads();   // all adjH reads complete before ssq overwrite (union)

    // ---- phase 8: consume 4; ssq write; agg -> hwa; Wg group-0 prefetch ----
    const float4* WgQ = (const float4*)Wg;
    float4 wg0, wg1, wg2, wg3;
    if (act) {
        wg0 = WgQ[0 * 25 + dg]; wg1 = WgQ[1 * 25 + dg];
        wg2 = WgQ[2 * 25 + dg]; wg3 = WgQ[3 * 25 + dg];
        AGG_CONSUME(4)
#pragma unroll
        for (int i = 0; i < 5; ++i)
            u.ssq[sb + i][dg] = hl[i][0]*hl[i][0] + hl[i][1]*hl[i][1]
                              + hl[i][2]*hl[i][2] + hl[i][3]*hl[i][3];
#pragma unroll
        for (int i = 0; i < 5; ++i) {
            float4 v; v.x = agg[i][0]; v.y = agg[i][1]; v.z = agg[i][2]; v.w = agg[i][3];
            *(float4*)&hwa[sb + i][d4] = v;   // hwa reads finished in adj-GEMM
        }
    }
    __syncthreads();

    if (t < S_) {
        float ss = 0.f;
#pragma unroll
        for (int j = 0; j < 25; ++j) ss += u.ssq[t][j];
        rinv[t] = s0 / fmaxf(sqrtf(ss), 1e-12f);
    }
    __syncthreads();

    // ---- normalize hl; hg = relu([h | agg] @ Wg) with weight prefetch ----
    float o[5][4] = {};
    if (act) {
#pragma unroll
        for (int i = 0; i < 5; ++i) {
            float f = rinv[sb + i];
#pragma unroll
            for (int j = 0; j < 4; ++j) hl[i][j] *= f;
        }
        for (int k = 0; k < 96; k += 4) {
            float4 n0 = WgQ[(k + 4) * 25 + dg], n1 = WgQ[(k + 5) * 25 + dg],
                   n2 = WgQ[(k + 6) * 25 + dg], n3 = WgQ[(k + 7) * 25 + dg];
            GEMM_STEP(o, hL, k, wg0, wg1, wg2, wg3)
            wg0 = n0; wg1 = n1; wg2 = n2; wg3 = n3;
        }
        {   // seam: finish h-half k=96, prefetch agg-half group 0
            float4 n0 = WgQ[100 * 25 + dg], n1 = WgQ[101 * 25 + dg],
                   n2 = WgQ[102 * 25 + dg], n3 = WgQ[103 * 25 + dg];
            GEMM_STEP(o, hL, 96, wg0, wg1, wg2, wg3)
            wg0 = n0; wg1 = n1; wg2 = n2; wg3 = n3;
        }
        for (int k = 0; k < 96; k += 4) {
            float4 n0 = WgQ[(100 + k + 4) * 25 + dg], n1 = WgQ[(100 + k + 5) * 25 + dg],
                   n2 = WgQ[(100 + k + 6) * 25 + dg], n3 = WgQ[(100 + k + 7) * 25 + dg];
            GEMM_STEP(o, hwa, k, wg0, wg1, wg2, wg3)
            wg0 = n0; wg1 = n1; wg2 = n2; wg3 = n3;
        }
        GEMM_STEP(o, hwa, 96, wg0, wg1, wg2, wg3)
#pragma unroll
        for (int i = 0; i < 5; ++i) {
#pragma unroll
            for (int j = 0; j < 4; ++j) o[i][j] = fmaxf(o[i][j], 0.f);
            u.ssq[sb + i][dg] = o[i][0]*o[i][0] + o[i][1]*o[i][1]
                              + o[i][2]*o[i][2] + o[i][3]*o[i][3];
        }
    }
    __syncthreads();

    if (t < S_) {
        float ss = 0.f;
#pragma unroll
        for (int j = 0; j < 25; ++j) ss += u.ssq[t][j];
        rinv2[t] = s1 / fmaxf(sqrtf(ss), 1e-12f);
    }
    __syncthreads();

    // ---- combine + NT store ----
    if (act) {
#pragma unroll
        for (int i = 0; i < 5; ++i) {
            float f = rinv2[sb + i];
            int row = b * S_ + sb + i;
            f4 ov;
            ov.x = hl[i][0] + o[i][0] * f;
            ov.y = hl[i][1] + o[i][1] * f;
            ov.z = hl[i][2] + o[i][2] * f;
            ov.w = hl[i][3] + o[i][3] * f;
            __builtin_nontemporal_store(ov, (f4*)(out + row * D_) + dg);
        }
    }
}

// ---------------------------------------------------------------------------
extern "C" void kernel_launch(void* const* d_in, const int* in_sizes, int n_in,
                              void* d_out, int out_size, void* d_ws, size_t ws_size,
                              hipStream_t stream) {
    (void)in_sizes; (void)n_in; (void)out_size; (void)d_ws; (void)ws_size;
    const int* inputs     = (const int*)d_in[0];
    const float* adj      = (const float*)d_in[1];
    // d_in[2] = item (unused by reference)
    const int* last_items = (const int*)d_in[3];
    const int* adj_items  = (const int*)d_in[4];
    const float* emb      = (const float*)d_in[5];
    const float* sW       = (const float*)d_in[6];
    const float* Wa       = (const float*)d_in[7];
    const float* Wq       = (const float*)d_in[8];
    const float* Wk       = (const float*)d_in[9];
    const float* Wg       = (const float*)d_in[10];
    const float* Wl       = (const float*)d_in[11];
    const int* adj_all    = (const int*)d_in[12];
    const float* num_w    = (const float*)d_in[13];

    float* out = (float*)d_out;

    fused_all<<<2 * B_, 256, 0, stream>>>(inputs, adj, emb, adj_all, num_w,
                                          sW, Wa, Wq, Wk, Wg,
                                          last_items, adj_items, Wl, out);
}